// Round 13
// baseline (499.284 us; speedup 1.0000x reference)
//
#include <hip/hip_runtime.h>
#include <hip/hip_bf16.h>

typedef unsigned short u16;
typedef __attribute__((ext_vector_type(8))) short bf16x8;
typedef __attribute__((ext_vector_type(4))) float f32x4;

#define NN 50000
#define NE 800000
#define SCAN_NB ((NN + 255) / 256)

__device__ __forceinline__ float bf2f(u16 u) { return __uint_as_float(((unsigned)u) << 16); }
__device__ __forceinline__ u16 f2bf(float f) {
  unsigned u = __float_as_uint(f);
  return (u16)((u + 0x7FFFu + ((u >> 16) & 1u)) >> 16);
}

// ---------------- CSR build ----------------
__global__ void k_hist(const int* __restrict__ ei, int* __restrict__ deg) {
  int i = blockIdx.x * 256 + threadIdx.x;
  if (i < NE) {
    int d = ei[NE + i];
    if (d >= 0 && d < NN) atomicAdd(&deg[d], 1);
  }
}

__global__ __launch_bounds__(256) void k_scan_a(const int* __restrict__ deg,
                                                int* __restrict__ bsum) {
  __shared__ int red[256];
  const int t = threadIdx.x;
  const int i = blockIdx.x * 256 + t;
  red[t] = (i < NN) ? deg[i] : 0;
  __syncthreads();
  #pragma unroll
  for (int s = 128; s > 0; s >>= 1) {
    if (t < s) red[t] += red[t + s];
    __syncthreads();
  }
  if (t == 0) bsum[blockIdx.x] = red[0];
}

__global__ __launch_bounds__(256) void k_scan_b(const int* __restrict__ bsum,
                                                int* __restrict__ boff,
                                                int* __restrict__ rowptr) {
  __shared__ int s[256];
  const int t = threadIdx.x;
  int v = (t < SCAN_NB) ? bsum[t] : 0;
  s[t] = v;
  __syncthreads();
  #pragma unroll
  for (int o = 1; o < 256; o <<= 1) {
    int u = (t >= o) ? s[t - o] : 0;
    __syncthreads();
    s[t] += u;
    __syncthreads();
  }
  if (t < SCAN_NB) boff[t] = s[t] - v;
  if (t == 255) rowptr[NN] = s[255];
}

__global__ __launch_bounds__(256) void k_scan_c(const int* __restrict__ deg,
                                                const int* __restrict__ boff,
                                                int* __restrict__ rowptr,
                                                int* __restrict__ cursor) {
  __shared__ int s[256];
  const int t = threadIdx.x;
  const int i = blockIdx.x * 256 + t;
  int v = (i < NN) ? deg[i] : 0;
  s[t] = v;
  __syncthreads();
  #pragma unroll
  for (int o = 1; o < 256; o <<= 1) {
    int u = (t >= o) ? s[t - o] : 0;
    __syncthreads();
    s[t] += u;
    __syncthreads();
  }
  if (i < NN) {
    int r = boff[blockIdx.x] + s[t] - v;
    rowptr[i] = r;
    cursor[i] = r;
  }
}

// emits slist[pos]=src and elist[pos]=eid (CSR-ordered edge list)
__global__ void k_scatter(const int* __restrict__ ei, int* __restrict__ cursor,
                          int* __restrict__ slist, int* __restrict__ elist) {
  int i = blockIdx.x * 256 + threadIdx.x;
  if (i < NE) {
    int d = ei[NE + i];
    if (d >= 0 && d < NN) {
      int pos = atomicAdd(&cursor[d], 1);
      if (pos >= 0 && pos < NE) {
        elist[pos] = i;
        int s = ei[i];
        slist[pos] = max(0, min(s, NN - 1));
      }
    }
  }
}

// ---------------- merged weight prep + deg zero ----------------
#define PREP_TOTAL 388432
__global__ void k_prep_all(
    const float* __restrict__ w00, const float* __restrict__ wq,
    const float* __restrict__ wedge, const float* __restrict__ wk,
    const float* __restrict__ we1, const float* __restrict__ we2, const float* __restrict__ we3,
    const float* __restrict__ wv, const float* __restrict__ wskip, const float* __restrict__ w1,
    u16* __restrict__ wB00t, u16* __restrict__ wqt, u16* __restrict__ BGQ,
    u16* __restrict__ wB1t, u16* __restrict__ wB2t, u16* __restrict__ wB3t,
    u16* __restrict__ Bt, u16* __restrict__ Bt1, int* __restrict__ deg) {
  int i = blockIdx.x * 256 + threadIdx.x;
  if (i < 2048) {
    int n = i >> 5, k = i & 31;
    wB00t[i] = (k < 16) ? f2bf(w00[k * 64 + n]) : (u16)0;
  } else if (i < 18432) {
    int i2 = i - 2048;
    int n = i2 >> 6, k = i2 & 63;
    wqt[i2] = f2bf(wq[k * 256 + n]);
  } else if (i < 149504) {
    int i2 = i - 18432;
    int col = i2 >> 8, k = i2 & 255;
    float v;
    if (col < 256) v = ((k >> 6) == (col >> 6)) ? wedge[(col & 63) * 256 + k] : 0.f;
    else { int c = col - 256; v = ((k >> 6) == (c >> 6)) ? wk[(c & 63) * 256 + k] : 0.f; }
    BGQ[i2] = f2bf(v);
  } else if (i < 150016) {
    int i2 = i - 149504;
    int n = i2 >> 3, k = i2 & 7;
    wB1t[i2] = f2bf(we1[k * 64 + n]);
  } else if (i < 154112) {
    int i2 = i - 150016;
    int n = i2 >> 6, k = i2 & 63;
    wB2t[i2] = f2bf(we2[k * 64 + n]);
  } else if (i < 158208) {
    int i2 = i - 154112;
    int n = i2 >> 6, k = i2 & 63;
    wB3t[i2] = f2bf(we3[k * 64 + n]);
  } else if (i < 305664) {
    int i2 = i - 158208;
    int col = i2 / 576, k = i2 - col * 576;
    float v;
    if (k < 256) v = ((k >> 6) == (col >> 6)) ? wedge[(k & 63) * 256 + col] : 0.f;
    else if (k < 512) { int k2 = k - 256; v = ((k2 >> 6) == (col >> 6)) ? wv[(k2 & 63) * 256 + col] : 0.f; }
    else v = wskip[(k - 512) * 256 + col];
    Bt[i2] = f2bf(v);
  } else if (i < 338432) {
    int i2 = i - 305664;
    int col = i2 >> 8, k = i2 & 255;
    Bt1[i2] = f2bf(w1[k * 128 + col]);
  } else if (i < PREP_TOTAL) {
    deg[i - 338432] = 0;
  }
}

// ---------------- node chain via MFMA: x -> x1 -> q -> {G, Qk} ----------------
__global__ __launch_bounds__(256) void k_ng(
    const float* __restrict__ x, const u16* __restrict__ wB00t, const float* __restrict__ b00,
    const u16* __restrict__ wqt, const float* __restrict__ bq,
    const u16* __restrict__ BGQ,
    u16* __restrict__ x1g, float* __restrict__ x1f,
    u16* __restrict__ Gg, u16* __restrict__ Qkg) {
  __shared__ u16 xs[64 * 32];
  __shared__ u16 x1s[64 * 72];
  __shared__ u16 qs[64 * 264];
  const int t = threadIdx.x;
  const int w = t >> 6, l = t & 63;
  const int quad = l >> 4, li = l & 15;
  const int n0 = blockIdx.x * 64;
  const f32x4 zc = {0.f, 0.f, 0.f, 0.f};

  for (int q = t; q < 2048; q += 256) {
    int row = q >> 5, k = q & 31;
    float v = (k < 16 && n0 + row < NN) ? x[(size_t)(n0 + row) * 16 + k] : 0.f;
    xs[row * 32 + k] = f2bf(v);
  }
  __syncthreads();

  {
    bf16x8 bf = *(const bf16x8*)(wB00t + (w * 16 + li) * 32 + quad * 8);
    float bc = b00[w * 16 + li];
    #pragma unroll
    for (int mt = 0; mt < 4; ++mt) {
      bf16x8 af = *(const bf16x8*)(xs + (mt * 16 + li) * 32 + quad * 8);
      f32x4 d = __builtin_amdgcn_mfma_f32_16x16x32_bf16(af, bf, zc, 0, 0, 0);
      #pragma unroll
      for (int r = 0; r < 4; ++r)
        x1s[(mt * 16 + quad * 4 + r) * 72 + w * 16 + li] = f2bf(fmaxf(d[r] + bc, 0.f));
    }
  }
  __syncthreads();

  #pragma unroll
  for (int it = 0; it < 2; ++it) {
    int i = (it * 256 + t) * 8;
    int row = i >> 6, col = i & 63;
    if (n0 + row < NN) {
      uint4 v = *(const uint4*)(x1s + row * 72 + col);
      *(uint4*)(x1g + (size_t)(n0 + row) * 64 + col) = v;
      const u16* pv = (const u16*)&v;
      float4 f0, f1;
      f0.x = bf2f(pv[0]); f0.y = bf2f(pv[1]); f0.z = bf2f(pv[2]); f0.w = bf2f(pv[3]);
      f1.x = bf2f(pv[4]); f1.y = bf2f(pv[5]); f1.z = bf2f(pv[6]); f1.w = bf2f(pv[7]);
      *(float4*)(x1f + (size_t)(n0 + row) * 64 + col) = f0;
      *(float4*)(x1f + (size_t)(n0 + row) * 64 + col + 4) = f1;
    }
  }

  {
    f32x4 acc[4][4];
    #pragma unroll
    for (int mt = 0; mt < 4; ++mt)
      #pragma unroll
      for (int nt = 0; nt < 4; ++nt) acc[mt][nt] = zc;
    const int colbase = w * 64;
    #pragma unroll
    for (int s = 0; s < 2; ++s) {
      bf16x8 bf[4];
      #pragma unroll
      for (int nt = 0; nt < 4; ++nt)
        bf[nt] = *(const bf16x8*)(wqt + (size_t)(colbase + nt * 16 + li) * 64 + s * 32 + quad * 8);
      #pragma unroll
      for (int mt = 0; mt < 4; ++mt) {
        bf16x8 af = *(const bf16x8*)(x1s + (mt * 16 + li) * 72 + s * 32 + quad * 8);
        #pragma unroll
        for (int nt = 0; nt < 4; ++nt)
          acc[mt][nt] = __builtin_amdgcn_mfma_f32_16x16x32_bf16(af, bf[nt], acc[mt][nt], 0, 0, 0);
      }
    }
    float bqc[4];
    #pragma unroll
    for (int nt = 0; nt < 4; ++nt) bqc[nt] = bq[colbase + nt * 16 + li];
    #pragma unroll
    for (int mt = 0; mt < 4; ++mt)
      #pragma unroll
      for (int nt = 0; nt < 4; ++nt)
        #pragma unroll
        for (int r = 0; r < 4; ++r)
          qs[(mt * 16 + quad * 4 + r) * 264 + colbase + nt * 16 + li] = f2bf(acc[mt][nt][r] + bqc[nt]);
  }
  __syncthreads();

  #pragma unroll
  for (int half = 0; half < 2; ++half) {
    f32x4 acc[4][4];
    #pragma unroll
    for (int mt = 0; mt < 4; ++mt)
      #pragma unroll
      for (int nt = 0; nt < 4; ++nt) acc[mt][nt] = zc;
    const int colbase = w * 64;
    const size_t bofs = (size_t)(half * 256) * 256;
    #pragma unroll
    for (int s = 0; s < 8; ++s) {
      bf16x8 bf[4];
      #pragma unroll
      for (int nt = 0; nt < 4; ++nt)
        bf[nt] = *(const bf16x8*)(BGQ + bofs + (size_t)(colbase + nt * 16 + li) * 256 + s * 32 + quad * 8);
      #pragma unroll
      for (int mt = 0; mt < 4; ++mt) {
        bf16x8 af = *(const bf16x8*)(qs + (mt * 16 + li) * 264 + s * 32 + quad * 8);
        #pragma unroll
        for (int nt = 0; nt < 4; ++nt)
          acc[mt][nt] = __builtin_amdgcn_mfma_f32_16x16x32_bf16(af, bf[nt], acc[mt][nt], 0, 0, 0);
      }
    }
    u16* dst = half ? Qkg : Gg;
    #pragma unroll
    for (int mt = 0; mt < 4; ++mt)
      #pragma unroll
      for (int r = 0; r < 4; ++r) {
        int node = n0 + mt * 16 + quad * 4 + r;
        if (node < NN) {
          #pragma unroll
          for (int nt = 0; nt < 4; ++nt)
            dst[(size_t)node * 256 + colbase + nt * 16 + li] = f2bf(acc[mt][nt][r]);
        }
      }
  }
}

// ---------------- edge MLP via MFMA bf16: gather ea by CSR order, sequential e3 write ----------------
#define EPB 128
#define APAD 72
__global__ __launch_bounds__(256) void k_edge_mlp(
    const float* __restrict__ ea, const int* __restrict__ elist,
    const u16* __restrict__ wB1t, const u16* __restrict__ wB2t, const u16* __restrict__ wB3t,
    const float* __restrict__ be1, const float* __restrict__ be2, const float* __restrict__ be3,
    u16* __restrict__ e3g) {
  __shared__ u16 actA[EPB * APAD];
  __shared__ u16 actB[EPB * APAD];
  const int t = threadIdx.x;
  const int w = t >> 6, l = t & 63;
  const int quad = l >> 4, li = l & 15;
  const int e0 = blockIdx.x * EPB;   // CSR position base
  const f32x4 zc = {0.f, 0.f, 0.f, 0.f};

  float b1c[4], b2c[4], b3c[4];
  #pragma unroll
  for (int nt = 0; nt < 4; ++nt) {
    b1c[nt] = be1[nt * 16 + li];
    b2c[nt] = be2[nt * 16 + li];
    b3c[nt] = be3[nt * 16 + li];
  }

  bf16x8 b1f[4];
  #pragma unroll
  for (int nt = 0; nt < 4; ++nt) {
    bf16x8 z = {};
    if (quad == 0) z = *(const bf16x8*)(wB1t + (nt * 16 + li) * 8);
    b1f[nt] = z;
  }
  #pragma unroll
  for (int mi = 0; mi < 2; ++mi) {
    const int mt = w * 2 + mi;
    bf16x8 af = {};
    if (quad == 0) {
      int eid = elist[e0 + mt * 16 + li];
      eid = max(0, min(eid, NE - 1));
      const float4* pa = (const float4*)(ea + (size_t)eid * 8);
      float4 p0 = pa[0], p1 = pa[1];
      af[0] = (short)f2bf(p0.x); af[1] = (short)f2bf(p0.y);
      af[2] = (short)f2bf(p0.z); af[3] = (short)f2bf(p0.w);
      af[4] = (short)f2bf(p1.x); af[5] = (short)f2bf(p1.y);
      af[6] = (short)f2bf(p1.z); af[7] = (short)f2bf(p1.w);
    }
    #pragma unroll
    for (int nt = 0; nt < 4; ++nt) {
      f32x4 d = __builtin_amdgcn_mfma_f32_16x16x32_bf16(af, b1f[nt], zc, 0, 0, 0);
      #pragma unroll
      for (int r = 0; r < 4; ++r)
        actA[(mt * 16 + quad * 4 + r) * APAD + nt * 16 + li] = f2bf(fmaxf(d[r] + b1c[nt], 0.f));
    }
  }
  __syncthreads();

  {
    bf16x8 bf[4][2];
    #pragma unroll
    for (int nt = 0; nt < 4; ++nt)
      #pragma unroll
      for (int kk = 0; kk < 2; ++kk)
        bf[nt][kk] = *(const bf16x8*)(wB2t + (nt * 16 + li) * 64 + kk * 32 + quad * 8);
    #pragma unroll
    for (int mi = 0; mi < 2; ++mi) {
      const int mt = w * 2 + mi;
      bf16x8 a0 = *(const bf16x8*)(actA + (mt * 16 + li) * APAD + quad * 8);
      bf16x8 a1 = *(const bf16x8*)(actA + (mt * 16 + li) * APAD + 32 + quad * 8);
      #pragma unroll
      for (int nt = 0; nt < 4; ++nt) {
        f32x4 d = __builtin_amdgcn_mfma_f32_16x16x32_bf16(a0, bf[nt][0], zc, 0, 0, 0);
        d = __builtin_amdgcn_mfma_f32_16x16x32_bf16(a1, bf[nt][1], d, 0, 0, 0);
        #pragma unroll
        for (int r = 0; r < 4; ++r)
          actB[(mt * 16 + quad * 4 + r) * APAD + nt * 16 + li] = f2bf(fmaxf(d[r] + b2c[nt], 0.f));
      }
    }
  }
  __syncthreads();

  {
    bf16x8 bf[4][2];
    #pragma unroll
    for (int nt = 0; nt < 4; ++nt)
      #pragma unroll
      for (int kk = 0; kk < 2; ++kk)
        bf[nt][kk] = *(const bf16x8*)(wB3t + (nt * 16 + li) * 64 + kk * 32 + quad * 8);
    #pragma unroll
    for (int mi = 0; mi < 2; ++mi) {
      const int mt = w * 2 + mi;
      bf16x8 a0 = *(const bf16x8*)(actB + (mt * 16 + li) * APAD + quad * 8);
      bf16x8 a1 = *(const bf16x8*)(actB + (mt * 16 + li) * APAD + 32 + quad * 8);
      #pragma unroll
      for (int nt = 0; nt < 4; ++nt) {
        f32x4 d = __builtin_amdgcn_mfma_f32_16x16x32_bf16(a0, bf[nt][0], zc, 0, 0, 0);
        d = __builtin_amdgcn_mfma_f32_16x16x32_bf16(a1, bf[nt][1], d, 0, 0, 0);
        #pragma unroll
        for (int r = 0; r < 4; ++r)
          actA[(mt * 16 + quad * 4 + r) * APAD + nt * 16 + li] = f2bf(fmaxf(d[r] + b3c[nt], 0.f));
      }
    }
  }
  __syncthreads();

  // sequential, fully coalesced e3 store
  #pragma unroll
  for (int it = 0; it < 4; ++it) {
    int flat = it * 2048 + t * 8;
    int el = flat >> 6, c = flat & 63;
    uint4 v = *(const uint4*)(actA + el * APAD + c);
    *(uint4*)(e3g + (size_t)(e0 + el) * 64 + c) = v;
  }
}

// ---------------- attention gather: sequential e3 (CSR order), fp32 x1 table ----------------
__global__ __launch_bounds__(256) void k_attn(
    const int* __restrict__ rowptr, const int* __restrict__ slist,
    u16* yo, const float* __restrict__ x1f, u16* gz, const u16* __restrict__ Qkg,
    const u16* __restrict__ e3g, float* __restrict__ bfac) {
  const int t = threadIdx.x;
  const int w = t >> 6;
  const int l = t & 63;
  const int grp = l >> 4;
  const int li = l & 15;
  const int chb = grp * 64 + li * 4;
  const int n = blockIdx.x * 4 + w;
  int base = rowptr[n];
  int end  = rowptr[n + 1];
  base = max(0, min(base, NE));
  end  = max(base, min(end, NE));
  if (l == 0) bfac[n] = (end > base) ? 1.f : 0.f;

  float Qkf[4], Gf[4];
  {
    ushort4 kv = *(const ushort4*)(Qkg + (size_t)n * 256 + chb);
    Qkf[0] = bf2f(kv.x); Qkf[1] = bf2f(kv.y); Qkf[2] = bf2f(kv.z); Qkf[3] = bf2f(kv.w);
    ushort4 gv = *(const ushort4*)(gz + (size_t)n * 256 + chb);
    Gf[0] = bf2f(gv.x); Gf[1] = bf2f(gv.y); Gf[2] = bf2f(gv.z); Gf[3] = bf2f(gv.w);
  }

  float s_run = 0.f;
  float y[4] = {0, 0, 0, 0}, zz[4] = {0, 0, 0, 0};
  int d = base;
  for (; d + 3 < end; d += 4) {
    int src[4];
    #pragma unroll
    for (int u = 0; u < 4; ++u) {
      int s = slist[d + u];
      src[u] = max(0, min(s, NN - 1));
    }
    float4 xv[4];
    ushort4 ev[4];
    #pragma unroll
    for (int u = 0; u < 4; ++u) {
      xv[u] = *(const float4*)(x1f + (size_t)src[u] * 64 + li * 4);
      ev[u] = *(const ushort4*)(e3g + (size_t)(d + u) * 64 + li * 4);
    }
    float ef[4][4], p[4];
    #pragma unroll
    for (int u = 0; u < 4; ++u) {
      ef[u][0] = bf2f(ev[u].x); ef[u][1] = bf2f(ev[u].y);
      ef[u][2] = bf2f(ev[u].z); ef[u][3] = bf2f(ev[u].w);
      p[u] = Qkf[0]*xv[u].x + Qkf[1]*xv[u].y + Qkf[2]*xv[u].z + Qkf[3]*xv[u].w
           + Gf[0]*ef[u][0] + Gf[1]*ef[u][1] + Gf[2]*ef[u][2] + Gf[3]*ef[u][3];
    }
    #pragma unroll
    for (int mk = 1; mk < 16; mk <<= 1) {
      p[0] += __shfl_xor(p[0], mk); p[1] += __shfl_xor(p[1], mk);
      p[2] += __shfl_xor(p[2], mk); p[3] += __shfl_xor(p[3], mk);
    }
    float wt[4];
    #pragma unroll
    for (int u = 0; u < 4; ++u) wt[u] = __expf(fminf(p[u] * 0.125f, 60.f));
    s_run += (wt[0] + wt[1]) + (wt[2] + wt[3]);
    #pragma unroll
    for (int u = 0; u < 4; ++u) {
      y[0] += wt[u]*xv[u].x; y[1] += wt[u]*xv[u].y;
      y[2] += wt[u]*xv[u].z; y[3] += wt[u]*xv[u].w;
      zz[0] += wt[u]*ef[u][0]; zz[1] += wt[u]*ef[u][1];
      zz[2] += wt[u]*ef[u][2]; zz[3] += wt[u]*ef[u][3];
    }
  }
  for (; d < end; ++d) {
    int src0 = slist[d];
    src0 = max(0, min(src0, NN - 1));
    float4 x0 = *(const float4*)(x1f + (size_t)src0 * 64 + li * 4);
    ushort4 e0 = *(const ushort4*)(e3g + (size_t)d * 64 + li * 4);
    float ef00 = bf2f(e0.x), ef01 = bf2f(e0.y), ef02 = bf2f(e0.z), ef03 = bf2f(e0.w);
    float p0 = Qkf[0]*x0.x + Qkf[1]*x0.y + Qkf[2]*x0.z + Qkf[3]*x0.w
             + Gf[0]*ef00 + Gf[1]*ef01 + Gf[2]*ef02 + Gf[3]*ef03;
    #pragma unroll
    for (int mk = 1; mk < 16; mk <<= 1) p0 += __shfl_xor(p0, mk);
    float w0 = __expf(fminf(p0 * 0.125f, 60.f));
    s_run += w0;
    y[0] += w0*x0.x; y[1] += w0*x0.y; y[2] += w0*x0.z; y[3] += w0*x0.w;
    zz[0] += w0*ef00; zz[1] += w0*ef01; zz[2] += w0*ef02; zz[3] += w0*ef03;
  }
  const float inv_s = 1.0f / (s_run + 1e-16f);
  ushort4 ynv, znv;
  ynv.x = f2bf(y[0] * inv_s); ynv.y = f2bf(y[1] * inv_s);
  ynv.z = f2bf(y[2] * inv_s); ynv.w = f2bf(y[3] * inv_s);
  znv.x = f2bf(zz[0] * inv_s); znv.y = f2bf(zz[1] * inv_s);
  znv.z = f2bf(zz[2] * inv_s); znv.w = f2bf(zz[3] * inv_s);
  *(ushort4*)(yo + (size_t)n * 256 + chb) = ynv;
  *(ushort4*)(gz + (size_t)n * 256 + chb) = znv;
}

// ---------------- fused post+head via MFMA ----------------
#define PM 64
#define PK 576
#define PAPAD 584
#define HAPAD 264
#define H1PAD 136
__global__ __launch_bounds__(256) void k_posthead(
    const u16* __restrict__ zng, const u16* __restrict__ yng, const u16* __restrict__ x1g,
    const u16* __restrict__ Bt, const float* __restrict__ bfac,
    const float* __restrict__ bedge, const float* __restrict__ bv, const float* __restrict__ bskip,
    const float* __restrict__ lng, const float* __restrict__ lnb,
    const u16* __restrict__ Bt1, const float* __restrict__ b1,
    const float* __restrict__ w2, const float* __restrict__ b2,
    float* __restrict__ outg) {
  __shared__ u16 As[PM * PAPAD];
  __shared__ float ps1[PM * 4];
  __shared__ float ps2[PM * 4];
  const int t = threadIdx.x;
  const int w = t >> 6, l = t & 63;
  const int quad = l >> 4, li = l & 15;
  const int n0 = blockIdx.x * PM;
  const f32x4 zc = {0.f, 0.f, 0.f, 0.f};

  for (int q = t; q < 2048; q += 256) {
    int row = q >> 5, off = (q & 31) * 8;
    uint4 vz = make_uint4(0, 0, 0, 0), vy = make_uint4(0, 0, 0, 0);
    if (n0 + row < NN) {
      vz = *(const uint4*)(zng + (size_t)(n0 + row) * 256 + off);
      vy = *(const uint4*)(yng + (size_t)(n0 + row) * 256 + off);
    }
    *(uint4*)(As + row * PAPAD + off) = vz;
    *(uint4*)(As + row * PAPAD + 256 + off) = vy;
  }
  for (int q = t; q < 512; q += 256) {
    int row = q >> 3, off = (q & 7) * 8;
    uint4 v = make_uint4(0, 0, 0, 0);
    if (n0 + row < NN) v = *(const uint4*)(x1g + (size_t)(n0 + row) * 64 + off);
    *(uint4*)(As + row * PAPAD + 512 + off) = v;
  }
  __syncthreads();

  f32x4 acc[4][4];
  #pragma unroll
  for (int mt = 0; mt < 4; ++mt)
    #pragma unroll
    for (int nt = 0; nt < 4; ++nt) acc[mt][nt] = zc;

  const int colbase = w * 64;
  #pragma unroll
  for (int s = 0; s < 18; ++s) {
    bf16x8 bf[4];
    #pragma unroll
    for (int nt = 0; nt < 4; ++nt)
      bf[nt] = *(const bf16x8*)(Bt + (size_t)(colbase + nt * 16 + li) * PK + s * 32 + quad * 8);
    #pragma unroll
    for (int mt = 0; mt < 4; ++mt) {
      bf16x8 af = *(const bf16x8*)(As + (mt * 16 + li) * PAPAD + s * 32 + quad * 8);
      #pragma unroll
      for (int nt = 0; nt < 4; ++nt)
        acc[mt][nt] = __builtin_amdgcn_mfma_f32_16x16x32_bf16(af, bf[nt], acc[mt][nt], 0, 0, 0);
    }
  }

  float beb[4], bs4[4], g4[4], lb4[4];
  #pragma unroll
  for (int nt = 0; nt < 4; ++nt) {
    int col = colbase + nt * 16 + li;
    beb[nt] = bedge[col] + bv[col];
    bs4[nt] = bskip[col]; g4[nt] = lng[col]; lb4[nt] = lnb[col];
  }
  #pragma unroll
  for (int mt = 0; mt < 4; ++mt) {
    #pragma unroll
    for (int r = 0; r < 4; ++r) {
      int node = n0 + mt * 16 + quad * 4 + r;
      float hasE = bfac[min(node, NN - 1)];
      #pragma unroll
      for (int nt = 0; nt < 4; ++nt)
        acc[mt][nt][r] += hasE * beb[nt] + bs4[nt];
    }
  }
  #pragma unroll
  for (int mt = 0; mt < 4; ++mt)
    #pragma unroll
    for (int r = 0; r < 4; ++r) {
      float s = acc[mt][0][r] + acc[mt][1][r] + acc[mt][2][r] + acc[mt][3][r];
      #pragma unroll
      for (int mk = 1; mk < 16; mk <<= 1) s += __shfl_xor(s, mk);
      if (li == 0) ps1[(mt * 16 + quad * 4 + r) * 4 + w] = s;
    }
  __syncthreads();
  float mu[4][4];
  #pragma unroll
  for (int mt = 0; mt < 4; ++mt)
    #pragma unroll
    for (int r = 0; r < 4; ++r) {
      float4 p = *(const float4*)(ps1 + (mt * 16 + quad * 4 + r) * 4);
      mu[mt][r] = (p.x + p.y + p.z + p.w) * (1.0f / 256.0f);
    }
  #pragma unroll
  for (int mt = 0; mt < 4; ++mt)
    #pragma unroll
    for (int r = 0; r < 4; ++r) {
      float m = mu[mt][r];
      float s = 0.f;
      #pragma unroll
      for (int nt = 0; nt < 4; ++nt) { float dd = acc[mt][nt][r] - m; s += dd * dd; }
      #pragma unroll
      for (int mk = 1; mk < 16; mk <<= 1) s += __shfl_xor(s, mk);
      if (li == 0) ps2[(mt * 16 + quad * 4 + r) * 4 + w] = s;
    }
  __syncthreads();
  u16* postL = As;
  u16* h1s   = As + 64 * HAPAD;
  #pragma unroll
  for (int mt = 0; mt < 4; ++mt)
    #pragma unroll
    for (int r = 0; r < 4; ++r) {
      float4 p = *(const float4*)(ps2 + (mt * 16 + quad * 4 + r) * 4);
      float rstd = rsqrtf((p.x + p.y + p.z + p.w) * (1.0f / 256.0f) + 1e-5f);
      float m = mu[mt][r];
      int row = mt * 16 + quad * 4 + r;
      #pragma unroll
      for (int nt = 0; nt < 4; ++nt) {
        int col = colbase + nt * 16 + li;
        postL[row * HAPAD + col] =
            f2bf(fmaxf((acc[mt][nt][r] - m) * rstd * g4[nt] + lb4[nt], 0.f));
      }
    }
  __syncthreads();

  {
    f32x4 hacc[4][2];
    #pragma unroll
    for (int mt = 0; mt < 4; ++mt)
      #pragma unroll
      for (int nt = 0; nt < 2; ++nt) hacc[mt][nt] = zc;
    const int hcb = w * 32;
    #pragma unroll
    for (int s = 0; s < 8; ++s) {
      bf16x8 bf[2];
      #pragma unroll
      for (int nt = 0; nt < 2; ++nt)
        bf[nt] = *(const bf16x8*)(Bt1 + (size_t)(hcb + nt * 16 + li) * 256 + s * 32 + quad * 8);
      #pragma unroll
      for (int mt = 0; mt < 4; ++mt) {
        bf16x8 af = *(const bf16x8*)(postL + (mt * 16 + li) * HAPAD + s * 32 + quad * 8);
        #pragma unroll
        for (int nt = 0; nt < 2; ++nt)
          hacc[mt][nt] = __builtin_amdgcn_mfma_f32_16x16x32_bf16(af, bf[nt], hacc[mt][nt], 0, 0, 0);
      }
    }
    float b1c[2];
    #pragma unroll
    for (int nt = 0; nt < 2; ++nt) b1c[nt] = b1[hcb + nt * 16 + li];
    #pragma unroll
    for (int mt = 0; mt < 4; ++mt)
      #pragma unroll
      for (int nt = 0; nt < 2; ++nt)
        #pragma unroll
        for (int r = 0; r < 4; ++r)
          h1s[(mt * 16 + quad * 4 + r) * H1PAD + hcb + nt * 16 + li] =
              f2bf(fmaxf(hacc[mt][nt][r] + b1c[nt], 0.f));
  }
  __syncthreads();

  const int node = t >> 2, c = t & 3;
  float lg = b2[c];
  const u16* hrow = h1s + node * H1PAD;
  #pragma unroll 4
  for (int j = 0; j < 128; ++j) lg += bf2f(hrow[j]) * w2[j * 4 + c];
  float mx = lg;
  #pragma unroll
  for (int mk = 1; mk < 4; mk <<= 1) mx = fmaxf(mx, __shfl_xor(mx, mk));
  float ex = __expf(lg - mx);
  float se = ex;
  #pragma unroll
  for (int mk = 1; mk < 4; mk <<= 1) se += __shfl_xor(se, mk);
  float res = lg - (mx + __logf(se));
  if (n0 + node < NN) outg[(size_t)(n0 + node) * 4 + c] = res;
}

extern "C" void kernel_launch(void* const* d_in, const int* in_sizes, int n_in,
                              void* d_out, int out_size, void* d_ws, size_t ws_size,
                              hipStream_t stream) {
  const float* x     = (const float*)d_in[0];
  const int*   ei    = (const int*)d_in[1];
  const float* ea    = (const float*)d_in[2];
  const float* w00   = (const float*)d_in[3];
  const float* b00   = (const float*)d_in[4];
  const float* we1   = (const float*)d_in[5];
  const float* be1   = (const float*)d_in[6];
  const float* we2   = (const float*)d_in[7];
  const float* be2   = (const float*)d_in[8];
  const float* we3   = (const float*)d_in[9];
  const float* be3   = (const float*)d_in[10];
  const float* wq    = (const float*)d_in[11];
  const float* bq    = (const float*)d_in[12];
  const float* wk    = (const float*)d_in[13];
  const float* bk    = (const float*)d_in[14];
  const float* wv    = (const float*)d_in[15];
  const float* bv    = (const float*)d_in[16];
  const float* wedge = (const float*)d_in[17];
  const float* bedge = (const float*)d_in[18];
  const float* wskip = (const float*)d_in[19];
  const float* bskip = (const float*)d_in[20];
  const float* lng   = (const float*)d_in[21];
  const float* lnb   = (const float*)d_in[22];
  const float* w1    = (const float*)d_in[23];
  const float* b1    = (const float*)d_in[24];
  const float* w2    = (const float*)d_in[25];
  const float* b2    = (const float*)d_in[26];
  float* outg = (float*)d_out;
  (void)bk;

  size_t off = 0;
  char* wsb = (char*)d_ws;
  auto carve = [&](size_t bytes) -> char* {
    char* r = wsb + off;
    off += (bytes + 255) & ~(size_t)255;
    return r;
  };
  u16* yg     = (u16*)carve((size_t)NN * 256 * 2);      // yn
  u16* Gg     = (u16*)carve((size_t)NN * 256 * 2);      // G -> zn
  u16* Qkg    = (u16*)carve((size_t)NN * 256 * 2);      // Qk
  u16* x1g    = (u16*)carve((size_t)NN * 64 * 2);
  float* x1f  = (float*)carve((size_t)NN * 64 * 4);     // fp32 x1 for k_attn
  u16* e3g    = (u16*)carve((size_t)NE * 64 * 2);       // e3 in CSR order
  int* deg    = (int*)carve((size_t)NN * 4);
  int* rowptr = (int*)carve((size_t)(NN + 1) * 4);
  int* cursor = (int*)carve((size_t)NN * 4);
  int* slist  = (int*)carve((size_t)NE * 4);
  int* elist  = (int*)carve((size_t)NE * 4);
  float* bfac = (float*)carve((size_t)NN * 4);
  int* bsum   = (int*)carve((size_t)SCAN_NB * 4);
  int* boff   = (int*)carve((size_t)SCAN_NB * 4);
  u16* wB00t  = (u16*)carve(2048 * 2);
  u16* wqt    = (u16*)carve(16384 * 2);
  u16* BGQ    = (u16*)carve((size_t)131072 * 2);
  u16* wB1t   = (u16*)carve(512 * 2);
  u16* wB2t   = (u16*)carve(4096 * 2);
  u16* wB3t   = (u16*)carve(4096 * 2);
  u16* Bt     = (u16*)carve((size_t)256 * 576 * 2);
  u16* Bt1    = (u16*)carve((size_t)128 * 256 * 2);
  if (off > ws_size) return;

  k_prep_all<<<(PREP_TOTAL + 255) / 256, 256, 0, stream>>>(
      w00, wq, wedge, wk, we1, we2, we3, wv, wskip, w1,
      wB00t, wqt, BGQ, wB1t, wB2t, wB3t, Bt, Bt1, deg);
  k_hist<<<NE / 256, 256, 0, stream>>>(ei, deg);
  k_scan_a<<<SCAN_NB, 256, 0, stream>>>(deg, bsum);
  k_scan_b<<<1, 256, 0, stream>>>(bsum, boff, rowptr);
  k_scan_c<<<SCAN_NB, 256, 0, stream>>>(deg, boff, rowptr, cursor);
  k_scatter<<<NE / 256, 256, 0, stream>>>(ei, cursor, slist, elist);
  k_ng<<<(NN + 63) / 64, 256, 0, stream>>>(x, wB00t, b00, wqt, bq, BGQ, x1g, x1f, Gg, Qkg);
  k_edge_mlp<<<NE / EPB, 256, 0, stream>>>(ea, elist, wB1t, wB2t, wB3t, be1, be2, be3, e3g);
  k_attn<<<NN / 4, 256, 0, stream>>>(rowptr, slist, yg, x1f, Gg, Qkg, e3g, bfac);
  k_posthead<<<(NN + PM - 1) / PM, 256, 0, stream>>>(
      Gg, yg, x1g, Bt, bfac, bedge, bv, bskip, lng, lnb, Bt1, b1, w2, b2, outg);
}

// Round 14
// 482.529 us; speedup vs baseline: 1.0347x; 1.0347x over previous
//
#include <hip/hip_runtime.h>
#include <hip/hip_bf16.h>

typedef unsigned short u16;
typedef __attribute__((ext_vector_type(8))) short bf16x8;
typedef __attribute__((ext_vector_type(4))) float f32x4;

#define NN 50000
#define NE 800000
#define SCAN_NB ((NN + 255) / 256)

__device__ __forceinline__ float bf2f(u16 u) { return __uint_as_float(((unsigned)u) << 16); }
__device__ __forceinline__ u16 f2bf(float f) {
  unsigned u = __float_as_uint(f);
  return (u16)((u + 0x7FFFu + ((u >> 16) & 1u)) >> 16);
}

// ---------------- CSR build ----------------
__global__ void k_hist(const int* __restrict__ ei, int* __restrict__ deg) {
  int i = blockIdx.x * 256 + threadIdx.x;
  if (i < NE) {
    int d = ei[NE + i];
    if (d >= 0 && d < NN) atomicAdd(&deg[d], 1);
  }
}

__global__ __launch_bounds__(256) void k_scan_a(const int* __restrict__ deg,
                                                int* __restrict__ bsum) {
  __shared__ int red[256];
  const int t = threadIdx.x;
  const int i = blockIdx.x * 256 + t;
  red[t] = (i < NN) ? deg[i] : 0;
  __syncthreads();
  #pragma unroll
  for (int s = 128; s > 0; s >>= 1) {
    if (t < s) red[t] += red[t + s];
    __syncthreads();
  }
  if (t == 0) bsum[blockIdx.x] = red[0];
}

__global__ __launch_bounds__(256) void k_scan_b(const int* __restrict__ bsum,
                                                int* __restrict__ boff,
                                                int* __restrict__ rowptr) {
  __shared__ int s[256];
  const int t = threadIdx.x;
  int v = (t < SCAN_NB) ? bsum[t] : 0;
  s[t] = v;
  __syncthreads();
  #pragma unroll
  for (int o = 1; o < 256; o <<= 1) {
    int u = (t >= o) ? s[t - o] : 0;
    __syncthreads();
    s[t] += u;
    __syncthreads();
  }
  if (t < SCAN_NB) boff[t] = s[t] - v;
  if (t == 255) rowptr[NN] = s[255];
}

__global__ __launch_bounds__(256) void k_scan_c(const int* __restrict__ deg,
                                                const int* __restrict__ boff,
                                                int* __restrict__ rowptr,
                                                int* __restrict__ cursor) {
  __shared__ int s[256];
  const int t = threadIdx.x;
  const int i = blockIdx.x * 256 + t;
  int v = (i < NN) ? deg[i] : 0;
  s[t] = v;
  __syncthreads();
  #pragma unroll
  for (int o = 1; o < 256; o <<= 1) {
    int u = (t >= o) ? s[t - o] : 0;
    __syncthreads();
    s[t] += u;
    __syncthreads();
  }
  if (i < NN) {
    int r = boff[blockIdx.x] + s[t] - v;
    rowptr[i] = r;
    cursor[i] = r;
  }
}

// emits slist[pos]=src (pre-clamped) and e2p[eid]=pos
__global__ void k_scatter(const int* __restrict__ ei, int* __restrict__ cursor,
                          int* __restrict__ slist, int* __restrict__ e2p) {
  int i = blockIdx.x * 256 + threadIdx.x;
  if (i < NE) {
    int d = ei[NE + i];
    if (d >= 0 && d < NN) {
      int pos = atomicAdd(&cursor[d], 1);
      if (pos >= 0 && pos < NE) {
        e2p[i] = pos;
        int s = ei[i];
        slist[pos] = max(0, min(s, NN - 1));
      }
    }
  }
}

// ---------------- merged weight prep + deg zero ----------------
#define PREP_TOTAL 388432
__global__ void k_prep_all(
    const float* __restrict__ w00, const float* __restrict__ wq,
    const float* __restrict__ wedge, const float* __restrict__ wk,
    const float* __restrict__ we1, const float* __restrict__ we2, const float* __restrict__ we3,
    const float* __restrict__ wv, const float* __restrict__ wskip, const float* __restrict__ w1,
    u16* __restrict__ wB00t, u16* __restrict__ wqt, u16* __restrict__ BGQ,
    u16* __restrict__ wB1t, u16* __restrict__ wB2t, u16* __restrict__ wB3t,
    u16* __restrict__ Bt, u16* __restrict__ Bt1, int* __restrict__ deg) {
  int i = blockIdx.x * 256 + threadIdx.x;
  if (i < 2048) {
    int n = i >> 5, k = i & 31;
    wB00t[i] = (k < 16) ? f2bf(w00[k * 64 + n]) : (u16)0;
  } else if (i < 18432) {
    int i2 = i - 2048;
    int n = i2 >> 6, k = i2 & 63;
    wqt[i2] = f2bf(wq[k * 256 + n]);
  } else if (i < 149504) {
    int i2 = i - 18432;
    int col = i2 >> 8, k = i2 & 255;
    float v;
    if (col < 256) v = ((k >> 6) == (col >> 6)) ? wedge[(col & 63) * 256 + k] : 0.f;
    else { int c = col - 256; v = ((k >> 6) == (c >> 6)) ? wk[(c & 63) * 256 + k] : 0.f; }
    BGQ[i2] = f2bf(v);
  } else if (i < 150016) {
    int i2 = i - 149504;
    int n = i2 >> 3, k = i2 & 7;
    wB1t[i2] = f2bf(we1[k * 64 + n]);
  } else if (i < 154112) {
    int i2 = i - 150016;
    int n = i2 >> 6, k = i2 & 63;
    wB2t[i2] = f2bf(we2[k * 64 + n]);
  } else if (i < 158208) {
    int i2 = i - 154112;
    int n = i2 >> 6, k = i2 & 63;
    wB3t[i2] = f2bf(we3[k * 64 + n]);
  } else if (i < 305664) {
    int i2 = i - 158208;
    int col = i2 / 576, k = i2 - col * 576;
    float v;
    if (k < 256) v = ((k >> 6) == (col >> 6)) ? wedge[(k & 63) * 256 + col] : 0.f;
    else if (k < 512) { int k2 = k - 256; v = ((k2 >> 6) == (col >> 6)) ? wv[(k2 & 63) * 256 + col] : 0.f; }
    else v = wskip[(k - 512) * 256 + col];
    Bt[i2] = f2bf(v);
  } else if (i < 338432) {
    int i2 = i - 305664;
    int col = i2 >> 8, k = i2 & 255;
    Bt1[i2] = f2bf(w1[k * 128 + col]);
  } else if (i < PREP_TOTAL) {
    deg[i - 338432] = 0;
  }
}

// ---------------- node chain via MFMA: x -> x1 -> q -> {G, Qk} ----------------
__global__ __launch_bounds__(256) void k_ng(
    const float* __restrict__ x, const u16* __restrict__ wB00t, const float* __restrict__ b00,
    const u16* __restrict__ wqt, const float* __restrict__ bq,
    const u16* __restrict__ BGQ,
    u16* __restrict__ x1g, u16* __restrict__ Gg, u16* __restrict__ Qkg) {
  __shared__ u16 xs[64 * 32];
  __shared__ u16 x1s[64 * 72];
  __shared__ u16 qs[64 * 264];
  const int t = threadIdx.x;
  const int w = t >> 6, l = t & 63;
  const int quad = l >> 4, li = l & 15;
  const int n0 = blockIdx.x * 64;
  const f32x4 zc = {0.f, 0.f, 0.f, 0.f};

  for (int q = t; q < 2048; q += 256) {
    int row = q >> 5, k = q & 31;
    float v = (k < 16 && n0 + row < NN) ? x[(size_t)(n0 + row) * 16 + k] : 0.f;
    xs[row * 32 + k] = f2bf(v);
  }
  __syncthreads();

  {
    bf16x8 bf = *(const bf16x8*)(wB00t + (w * 16 + li) * 32 + quad * 8);
    float bc = b00[w * 16 + li];
    #pragma unroll
    for (int mt = 0; mt < 4; ++mt) {
      bf16x8 af = *(const bf16x8*)(xs + (mt * 16 + li) * 32 + quad * 8);
      f32x4 d = __builtin_amdgcn_mfma_f32_16x16x32_bf16(af, bf, zc, 0, 0, 0);
      #pragma unroll
      for (int r = 0; r < 4; ++r)
        x1s[(mt * 16 + quad * 4 + r) * 72 + w * 16 + li] = f2bf(fmaxf(d[r] + bc, 0.f));
    }
  }
  __syncthreads();

  #pragma unroll
  for (int it = 0; it < 2; ++it) {
    int i = (it * 256 + t) * 8;
    int row = i >> 6, col = i & 63;
    if (n0 + row < NN)
      *(uint4*)(x1g + (size_t)(n0 + row) * 64 + col) = *(const uint4*)(x1s + row * 72 + col);
  }

  {
    f32x4 acc[4][4];
    #pragma unroll
    for (int mt = 0; mt < 4; ++mt)
      #pragma unroll
      for (int nt = 0; nt < 4; ++nt) acc[mt][nt] = zc;
    const int colbase = w * 64;
    #pragma unroll
    for (int s = 0; s < 2; ++s) {
      bf16x8 bf[4];
      #pragma unroll
      for (int nt = 0; nt < 4; ++nt)
        bf[nt] = *(const bf16x8*)(wqt + (size_t)(colbase + nt * 16 + li) * 64 + s * 32 + quad * 8);
      #pragma unroll
      for (int mt = 0; mt < 4; ++mt) {
        bf16x8 af = *(const bf16x8*)(x1s + (mt * 16 + li) * 72 + s * 32 + quad * 8);
        #pragma unroll
        for (int nt = 0; nt < 4; ++nt)
          acc[mt][nt] = __builtin_amdgcn_mfma_f32_16x16x32_bf16(af, bf[nt], acc[mt][nt], 0, 0, 0);
      }
    }
    float bqc[4];
    #pragma unroll
    for (int nt = 0; nt < 4; ++nt) bqc[nt] = bq[colbase + nt * 16 + li];
    #pragma unroll
    for (int mt = 0; mt < 4; ++mt)
      #pragma unroll
      for (int nt = 0; nt < 4; ++nt)
        #pragma unroll
        for (int r = 0; r < 4; ++r)
          qs[(mt * 16 + quad * 4 + r) * 264 + colbase + nt * 16 + li] = f2bf(acc[mt][nt][r] + bqc[nt]);
  }
  __syncthreads();

  #pragma unroll
  for (int half = 0; half < 2; ++half) {
    f32x4 acc[4][4];
    #pragma unroll
    for (int mt = 0; mt < 4; ++mt)
      #pragma unroll
      for (int nt = 0; nt < 4; ++nt) acc[mt][nt] = zc;
    const int colbase = w * 64;
    const size_t bofs = (size_t)(half * 256) * 256;
    #pragma unroll
    for (int s = 0; s < 8; ++s) {
      bf16x8 bf[4];
      #pragma unroll
      for (int nt = 0; nt < 4; ++nt)
        bf[nt] = *(const bf16x8*)(BGQ + bofs + (size_t)(colbase + nt * 16 + li) * 256 + s * 32 + quad * 8);
      #pragma unroll
      for (int mt = 0; mt < 4; ++mt) {
        bf16x8 af = *(const bf16x8*)(qs + (mt * 16 + li) * 264 + s * 32 + quad * 8);
        #pragma unroll
        for (int nt = 0; nt < 4; ++nt)
          acc[mt][nt] = __builtin_amdgcn_mfma_f32_16x16x32_bf16(af, bf[nt], acc[mt][nt], 0, 0, 0);
      }
    }
    u16* dst = half ? Qkg : Gg;
    #pragma unroll
    for (int mt = 0; mt < 4; ++mt)
      #pragma unroll
      for (int r = 0; r < 4; ++r) {
        int node = n0 + mt * 16 + quad * 4 + r;
        if (node < NN) {
          #pragma unroll
          for (int nt = 0; nt < 4; ++nt)
            dst[(size_t)node * 256 + colbase + nt * 16 + li] = f2bf(acc[mt][nt][r]);
        }
      }
  }
}

// ---------------- edge MLP via MFMA bf16, output scattered to CSR order ----------------
#define EPB 128
#define APAD 72
__global__ __launch_bounds__(256) void k_edge_mlp(
    const float* __restrict__ ea,
    const u16* __restrict__ wB1t, const u16* __restrict__ wB2t, const u16* __restrict__ wB3t,
    const float* __restrict__ be1, const float* __restrict__ be2, const float* __restrict__ be3,
    const int* __restrict__ e2p, u16* __restrict__ e3g) {
  __shared__ u16 actA[EPB * APAD];
  __shared__ u16 actB[EPB * APAD];
  const int t = threadIdx.x;
  const int w = t >> 6, l = t & 63;
  const int quad = l >> 4, li = l & 15;
  const int e0 = blockIdx.x * EPB;
  const f32x4 zc = {0.f, 0.f, 0.f, 0.f};

  float b1c[4], b2c[4], b3c[4];
  #pragma unroll
  for (int nt = 0; nt < 4; ++nt) {
    b1c[nt] = be1[nt * 16 + li];
    b2c[nt] = be2[nt * 16 + li];
    b3c[nt] = be3[nt * 16 + li];
  }

  bf16x8 b1f[4];
  #pragma unroll
  for (int nt = 0; nt < 4; ++nt) {
    bf16x8 z = {};
    if (quad == 0) z = *(const bf16x8*)(wB1t + (nt * 16 + li) * 8);
    b1f[nt] = z;
  }
  #pragma unroll
  for (int mi = 0; mi < 2; ++mi) {
    const int mt = w * 2 + mi;
    bf16x8 af = {};
    if (quad == 0) {
      const float4* pa = (const float4*)(ea + (size_t)(e0 + mt * 16 + li) * 8);
      float4 p0 = pa[0], p1 = pa[1];
      af[0] = (short)f2bf(p0.x); af[1] = (short)f2bf(p0.y);
      af[2] = (short)f2bf(p0.z); af[3] = (short)f2bf(p0.w);
      af[4] = (short)f2bf(p1.x); af[5] = (short)f2bf(p1.y);
      af[6] = (short)f2bf(p1.z); af[7] = (short)f2bf(p1.w);
    }
    #pragma unroll
    for (int nt = 0; nt < 4; ++nt) {
      f32x4 d = __builtin_amdgcn_mfma_f32_16x16x32_bf16(af, b1f[nt], zc, 0, 0, 0);
      #pragma unroll
      for (int r = 0; r < 4; ++r)
        actA[(mt * 16 + quad * 4 + r) * APAD + nt * 16 + li] = f2bf(fmaxf(d[r] + b1c[nt], 0.f));
    }
  }
  __syncthreads();

  {
    bf16x8 bf[4][2];
    #pragma unroll
    for (int nt = 0; nt < 4; ++nt)
      #pragma unroll
      for (int kk = 0; kk < 2; ++kk)
        bf[nt][kk] = *(const bf16x8*)(wB2t + (nt * 16 + li) * 64 + kk * 32 + quad * 8);
    #pragma unroll
    for (int mi = 0; mi < 2; ++mi) {
      const int mt = w * 2 + mi;
      bf16x8 a0 = *(const bf16x8*)(actA + (mt * 16 + li) * APAD + quad * 8);
      bf16x8 a1 = *(const bf16x8*)(actA + (mt * 16 + li) * APAD + 32 + quad * 8);
      #pragma unroll
      for (int nt = 0; nt < 4; ++nt) {
        f32x4 d = __builtin_amdgcn_mfma_f32_16x16x32_bf16(a0, bf[nt][0], zc, 0, 0, 0);
        d = __builtin_amdgcn_mfma_f32_16x16x32_bf16(a1, bf[nt][1], d, 0, 0, 0);
        #pragma unroll
        for (int r = 0; r < 4; ++r)
          actB[(mt * 16 + quad * 4 + r) * APAD + nt * 16 + li] = f2bf(fmaxf(d[r] + b2c[nt], 0.f));
      }
    }
  }
  __syncthreads();

  {
    bf16x8 bf[4][2];
    #pragma unroll
    for (int nt = 0; nt < 4; ++nt)
      #pragma unroll
      for (int kk = 0; kk < 2; ++kk)
        bf[nt][kk] = *(const bf16x8*)(wB3t + (nt * 16 + li) * 64 + kk * 32 + quad * 8);
    #pragma unroll
    for (int mi = 0; mi < 2; ++mi) {
      const int mt = w * 2 + mi;
      bf16x8 a0 = *(const bf16x8*)(actB + (mt * 16 + li) * APAD + quad * 8);
      bf16x8 a1 = *(const bf16x8*)(actB + (mt * 16 + li) * APAD + 32 + quad * 8);
      #pragma unroll
      for (int nt = 0; nt < 4; ++nt) {
        f32x4 d = __builtin_amdgcn_mfma_f32_16x16x32_bf16(a0, bf[nt][0], zc, 0, 0, 0);
        d = __builtin_amdgcn_mfma_f32_16x16x32_bf16(a1, bf[nt][1], d, 0, 0, 0);
        #pragma unroll
        for (int r = 0; r < 4; ++r)
          actA[(mt * 16 + quad * 4 + r) * APAD + nt * 16 + li] = f2bf(fmaxf(d[r] + b3c[nt], 0.f));
      }
    }
  }
  __syncthreads();

  #pragma unroll
  for (int it = 0; it < 4; ++it) {
    int flat = it * 2048 + t * 8;
    int el = flat >> 6, c = flat & 63;
    int pos = e2p[e0 + el];
    pos = ((unsigned)pos <= (unsigned)(NE - 1)) ? pos : NE;
    uint4 v = *(const uint4*)(actA + el * APAD + c);
    *(uint4*)(e3g + (size_t)pos * 64 + c) = v;
  }
}

// ---------------- attention gather: sequential e3 (CSR order), bf16 x1 table ----------------
__global__ __launch_bounds__(256) void k_attn(
    const int* __restrict__ rowptr, const int* __restrict__ slist,
    u16* yo, const u16* __restrict__ x1g, u16* gz, const u16* __restrict__ Qkg,
    const u16* __restrict__ e3g, float* __restrict__ bfac) {
  const int t = threadIdx.x;
  const int w = t >> 6;
  const int l = t & 63;
  const int grp = l >> 4;
  const int li = l & 15;
  const int chb = grp * 64 + li * 4;
  const int n = blockIdx.x * 4 + w;
  int base = rowptr[n];
  int end  = rowptr[n + 1];
  base = max(0, min(base, NE));
  end  = max(base, min(end, NE));
  if (l == 0) bfac[n] = (end > base) ? 1.f : 0.f;

  float Qkf[4], Gf[4];
  {
    ushort4 kv = *(const ushort4*)(Qkg + (size_t)n * 256 + chb);
    Qkf[0] = bf2f(kv.x); Qkf[1] = bf2f(kv.y); Qkf[2] = bf2f(kv.z); Qkf[3] = bf2f(kv.w);
    ushort4 gv = *(const ushort4*)(gz + (size_t)n * 256 + chb);
    Gf[0] = bf2f(gv.x); Gf[1] = bf2f(gv.y); Gf[2] = bf2f(gv.z); Gf[3] = bf2f(gv.w);
  }

  float s_run = 0.f;
  float y[4] = {0, 0, 0, 0}, zz[4] = {0, 0, 0, 0};
  int d = base;
  for (; d + 1 < end; d += 2) {
    // slist entries are pre-clamped by k_scatter; no per-edge clamp needed
    int src0 = slist[d], src1 = slist[d + 1];
    ushort4 x0 = *(const ushort4*)(x1g + (size_t)src0 * 64 + li * 4);
    ushort4 e0 = *(const ushort4*)(e3g + (size_t)d * 64 + li * 4);
    ushort4 x1v = *(const ushort4*)(x1g + (size_t)src1 * 64 + li * 4);
    ushort4 e1 = *(const ushort4*)(e3g + (size_t)(d + 1) * 64 + li * 4);
    float xf00 = bf2f(x0.x), xf01 = bf2f(x0.y), xf02 = bf2f(x0.z), xf03 = bf2f(x0.w);
    float ef00 = bf2f(e0.x), ef01 = bf2f(e0.y), ef02 = bf2f(e0.z), ef03 = bf2f(e0.w);
    float xf10 = bf2f(x1v.x), xf11 = bf2f(x1v.y), xf12 = bf2f(x1v.z), xf13 = bf2f(x1v.w);
    float ef10 = bf2f(e1.x), ef11 = bf2f(e1.y), ef12 = bf2f(e1.z), ef13 = bf2f(e1.w);
    float p0 = Qkf[0]*xf00 + Qkf[1]*xf01 + Qkf[2]*xf02 + Qkf[3]*xf03
             + Gf[0]*ef00 + Gf[1]*ef01 + Gf[2]*ef02 + Gf[3]*ef03;
    float p1 = Qkf[0]*xf10 + Qkf[1]*xf11 + Qkf[2]*xf12 + Qkf[3]*xf13
             + Gf[0]*ef10 + Gf[1]*ef11 + Gf[2]*ef12 + Gf[3]*ef13;
    #pragma unroll
    for (int mk = 1; mk < 16; mk <<= 1) { p0 += __shfl_xor(p0, mk); p1 += __shfl_xor(p1, mk); }
    float w0 = __expf(fminf(p0 * 0.125f, 60.f));
    float w1 = __expf(fminf(p1 * 0.125f, 60.f));
    s_run += w0 + w1;
    y[0] += w0*xf00 + w1*xf10; y[1] += w0*xf01 + w1*xf11;
    y[2] += w0*xf02 + w1*xf12; y[3] += w0*xf03 + w1*xf13;
    zz[0] += w0*ef00 + w1*ef10; zz[1] += w0*ef01 + w1*ef11;
    zz[2] += w0*ef02 + w1*ef12; zz[3] += w0*ef03 + w1*ef13;
  }
  if (d < end) {
    int src0 = slist[d];
    ushort4 x0 = *(const ushort4*)(x1g + (size_t)src0 * 64 + li * 4);
    ushort4 e0 = *(const ushort4*)(e3g + (size_t)d * 64 + li * 4);
    float xf00 = bf2f(x0.x), xf01 = bf2f(x0.y), xf02 = bf2f(x0.z), xf03 = bf2f(x0.w);
    float ef00 = bf2f(e0.x), ef01 = bf2f(e0.y), ef02 = bf2f(e0.z), ef03 = bf2f(e0.w);
    float p0 = Qkf[0]*xf00 + Qkf[1]*xf01 + Qkf[2]*xf02 + Qkf[3]*xf03
             + Gf[0]*ef00 + Gf[1]*ef01 + Gf[2]*ef02 + Gf[3]*ef03;
    #pragma unroll
    for (int mk = 1; mk < 16; mk <<= 1) p0 += __shfl_xor(p0, mk);
    float w0 = __expf(fminf(p0 * 0.125f, 60.f));
    s_run += w0;
    y[0] += w0*xf00; y[1] += w0*xf01; y[2] += w0*xf02; y[3] += w0*xf03;
    zz[0] += w0*ef00; zz[1] += w0*ef01; zz[2] += w0*ef02; zz[3] += w0*ef03;
  }
  const float inv_s = 1.0f / (s_run + 1e-16f);
  ushort4 ynv, znv;
  ynv.x = f2bf(y[0] * inv_s); ynv.y = f2bf(y[1] * inv_s);
  ynv.z = f2bf(y[2] * inv_s); ynv.w = f2bf(y[3] * inv_s);
  znv.x = f2bf(zz[0] * inv_s); znv.y = f2bf(zz[1] * inv_s);
  znv.z = f2bf(zz[2] * inv_s); znv.w = f2bf(zz[3] * inv_s);
  *(ushort4*)(yo + (size_t)n * 256 + chb) = ynv;
  *(ushort4*)(gz + (size_t)n * 256 + chb) = znv;
}

// ---------------- fused post+head via MFMA ----------------
#define PM 64
#define PK 576
#define PAPAD 584
#define HAPAD 264
#define H1PAD 136
__global__ __launch_bounds__(256) void k_posthead(
    const u16* __restrict__ zng, const u16* __restrict__ yng, const u16* __restrict__ x1g,
    const u16* __restrict__ Bt, const float* __restrict__ bfac,
    const float* __restrict__ bedge, const float* __restrict__ bv, const float* __restrict__ bskip,
    const float* __restrict__ lng, const float* __restrict__ lnb,
    const u16* __restrict__ Bt1, const float* __restrict__ b1,
    const float* __restrict__ w2, const float* __restrict__ b2,
    float* __restrict__ outg) {
  __shared__ u16 As[PM * PAPAD];
  __shared__ float ps1[PM * 4];
  __shared__ float ps2[PM * 4];
  const int t = threadIdx.x;
  const int w = t >> 6, l = t & 63;
  const int quad = l >> 4, li = l & 15;
  const int n0 = blockIdx.x * PM;
  const f32x4 zc = {0.f, 0.f, 0.f, 0.f};

  for (int q = t; q < 2048; q += 256) {
    int row = q >> 5, off = (q & 31) * 8;
    uint4 vz = make_uint4(0, 0, 0, 0), vy = make_uint4(0, 0, 0, 0);
    if (n0 + row < NN) {
      vz = *(const uint4*)(zng + (size_t)(n0 + row) * 256 + off);
      vy = *(const uint4*)(yng + (size_t)(n0 + row) * 256 + off);
    }
    *(uint4*)(As + row * PAPAD + off) = vz;
    *(uint4*)(As + row * PAPAD + 256 + off) = vy;
  }
  for (int q = t; q < 512; q += 256) {
    int row = q >> 3, off = (q & 7) * 8;
    uint4 v = make_uint4(0, 0, 0, 0);
    if (n0 + row < NN) v = *(const uint4*)(x1g + (size_t)(n0 + row) * 64 + off);
    *(uint4*)(As + row * PAPAD + 512 + off) = v;
  }
  __syncthreads();

  f32x4 acc[4][4];
  #pragma unroll
  for (int mt = 0; mt < 4; ++mt)
    #pragma unroll
    for (int nt = 0; nt < 4; ++nt) acc[mt][nt] = zc;

  const int colbase = w * 64;
  #pragma unroll
  for (int s = 0; s < 18; ++s) {
    bf16x8 bf[4];
    #pragma unroll
    for (int nt = 0; nt < 4; ++nt)
      bf[nt] = *(const bf16x8*)(Bt + (size_t)(colbase + nt * 16 + li) * PK + s * 32 + quad * 8);
    #pragma unroll
    for (int mt = 0; mt < 4; ++mt) {
      bf16x8 af = *(const bf16x8*)(As + (mt * 16 + li) * PAPAD + s * 32 + quad * 8);
      #pragma unroll
      for (int nt = 0; nt < 4; ++nt)
        acc[mt][nt] = __builtin_amdgcn_mfma_f32_16x16x32_bf16(af, bf[nt], acc[mt][nt], 0, 0, 0);
    }
  }

  float beb[4], bs4[4], g4[4], lb4[4];
  #pragma unroll
  for (int nt = 0; nt < 4; ++nt) {
    int col = colbase + nt * 16 + li;
    beb[nt] = bedge[col] + bv[col];
    bs4[nt] = bskip[col]; g4[nt] = lng[col]; lb4[nt] = lnb[col];
  }
  #pragma unroll
  for (int mt = 0; mt < 4; ++mt) {
    #pragma unroll
    for (int r = 0; r < 4; ++r) {
      int node = n0 + mt * 16 + quad * 4 + r;
      float hasE = bfac[min(node, NN - 1)];
      #pragma unroll
      for (int nt = 0; nt < 4; ++nt)
        acc[mt][nt][r] += hasE * beb[nt] + bs4[nt];
    }
  }
  #pragma unroll
  for (int mt = 0; mt < 4; ++mt)
    #pragma unroll
    for (int r = 0; r < 4; ++r) {
      float s = acc[mt][0][r] + acc[mt][1][r] + acc[mt][2][r] + acc[mt][3][r];
      #pragma unroll
      for (int mk = 1; mk < 16; mk <<= 1) s += __shfl_xor(s, mk);
      if (li == 0) ps1[(mt * 16 + quad * 4 + r) * 4 + w] = s;
    }
  __syncthreads();
  float mu[4][4];
  #pragma unroll
  for (int mt = 0; mt < 4; ++mt)
    #pragma unroll
    for (int r = 0; r < 4; ++r) {
      float4 p = *(const float4*)(ps1 + (mt * 16 + quad * 4 + r) * 4);
      mu[mt][r] = (p.x + p.y + p.z + p.w) * (1.0f / 256.0f);
    }
  #pragma unroll
  for (int mt = 0; mt < 4; ++mt)
    #pragma unroll
    for (int r = 0; r < 4; ++r) {
      float m = mu[mt][r];
      float s = 0.f;
      #pragma unroll
      for (int nt = 0; nt < 4; ++nt) { float dd = acc[mt][nt][r] - m; s += dd * dd; }
      #pragma unroll
      for (int mk = 1; mk < 16; mk <<= 1) s += __shfl_xor(s, mk);
      if (li == 0) ps2[(mt * 16 + quad * 4 + r) * 4 + w] = s;
    }
  __syncthreads();
  u16* postL = As;
  u16* h1s   = As + 64 * HAPAD;
  #pragma unroll
  for (int mt = 0; mt < 4; ++mt)
    #pragma unroll
    for (int r = 0; r < 4; ++r) {
      float4 p = *(const float4*)(ps2 + (mt * 16 + quad * 4 + r) * 4);
      float rstd = rsqrtf((p.x + p.y + p.z + p.w) * (1.0f / 256.0f) + 1e-5f);
      float m = mu[mt][r];
      int row = mt * 16 + quad * 4 + r;
      #pragma unroll
      for (int nt = 0; nt < 4; ++nt) {
        int col = colbase + nt * 16 + li;
        postL[row * HAPAD + col] =
            f2bf(fmaxf((acc[mt][nt][r] - m) * rstd * g4[nt] + lb4[nt], 0.f));
      }
    }
  __syncthreads();

  {
    f32x4 hacc[4][2];
    #pragma unroll
    for (int mt = 0; mt < 4; ++mt)
      #pragma unroll
      for (int nt = 0; nt < 2; ++nt) hacc[mt][nt] = zc;
    const int hcb = w * 32;
    #pragma unroll
    for (int s = 0; s < 8; ++s) {
      bf16x8 bf[2];
      #pragma unroll
      for (int nt = 0; nt < 2; ++nt)
        bf[nt] = *(const bf16x8*)(Bt1 + (size_t)(hcb + nt * 16 + li) * 256 + s * 32 + quad * 8);
      #pragma unroll
      for (int mt = 0; mt < 4; ++mt) {
        bf16x8 af = *(const bf16x8*)(postL + (mt * 16 + li) * HAPAD + s * 32 + quad * 8);
        #pragma unroll
        for (int nt = 0; nt < 2; ++nt)
          hacc[mt][nt] = __builtin_amdgcn_mfma_f32_16x16x32_bf16(af, bf[nt], hacc[mt][nt], 0, 0, 0);
      }
    }
    float b1c[2];
    #pragma unroll
    for (int nt = 0; nt < 2; ++nt) b1c[nt] = b1[hcb + nt * 16 + li];
    #pragma unroll
    for (int mt = 0; mt < 4; ++mt)
      #pragma unroll
      for (int nt = 0; nt < 2; ++nt)
        #pragma unroll
        for (int r = 0; r < 4; ++r)
          h1s[(mt * 16 + quad * 4 + r) * H1PAD + hcb + nt * 16 + li] =
              f2bf(fmaxf(hacc[mt][nt][r] + b1c[nt], 0.f));
  }
  __syncthreads();

  const int node = t >> 2, c = t & 3;
  float lg = b2[c];
  const u16* hrow = h1s + node * H1PAD;
  #pragma unroll 4
  for (int j = 0; j < 128; ++j) lg += bf2f(hrow[j]) * w2[j * 4 + c];
  float mx = lg;
  #pragma unroll
  for (int mk = 1; mk < 4; mk <<= 1) mx = fmaxf(mx, __shfl_xor(mx, mk));
  float ex = __expf(lg - mx);
  float se = ex;
  #pragma unroll
  for (int mk = 1; mk < 4; mk <<= 1) se += __shfl_xor(se, mk);
  float res = lg - (mx + __logf(se));
  if (n0 + node < NN) outg[(size_t)(n0 + node) * 4 + c] = res;
}

extern "C" void kernel_launch(void* const* d_in, const int* in_sizes, int n_in,
                              void* d_out, int out_size, void* d_ws, size_t ws_size,
                              hipStream_t stream) {
  const float* x     = (const float*)d_in[0];
  const int*   ei    = (const int*)d_in[1];
  const float* ea    = (const float*)d_in[2];
  const float* w00   = (const float*)d_in[3];
  const float* b00   = (const float*)d_in[4];
  const float* we1   = (const float*)d_in[5];
  const float* be1   = (const float*)d_in[6];
  const float* we2   = (const float*)d_in[7];
  const float* be2   = (const float*)d_in[8];
  const float* we3   = (const float*)d_in[9];
  const float* be3   = (const float*)d_in[10];
  const float* wq    = (const float*)d_in[11];
  const float* bq    = (const float*)d_in[12];
  const float* wk    = (const float*)d_in[13];
  const float* bk    = (const float*)d_in[14];
  const float* wv    = (const float*)d_in[15];
  const float* bv    = (const float*)d_in[16];
  const float* wedge = (const float*)d_in[17];
  const float* bedge = (const float*)d_in[18];
  const float* wskip = (const float*)d_in[19];
  const float* bskip = (const float*)d_in[20];
  const float* lng   = (const float*)d_in[21];
  const float* lnb   = (const float*)d_in[22];
  const float* w1    = (const float*)d_in[23];
  const float* b1    = (const float*)d_in[24];
  const float* w2    = (const float*)d_in[25];
  const float* b2    = (const float*)d_in[26];
  float* outg = (float*)d_out;
  (void)bk;

  size_t off = 0;
  char* wsb = (char*)d_ws;
  auto carve = [&](size_t bytes) -> char* {
    char* r = wsb + off;
    off += (bytes + 255) & ~(size_t)255;
    return r;
  };
  u16* yg     = (u16*)carve((size_t)NN * 256 * 2);      // yn
  u16* Gg     = (u16*)carve((size_t)NN * 256 * 2);      // G -> zn
  u16* Qkg    = (u16*)carve((size_t)NN * 256 * 2);      // Qk
  u16* x1g    = (u16*)carve((size_t)NN * 64 * 2);
  u16* e3g    = (u16*)carve((size_t)(NE + 1) * 64 * 2); // e3 in CSR order (+1 scratch row)
  int* deg    = (int*)carve((size_t)NN * 4);
  int* rowptr = (int*)carve((size_t)(NN + 1) * 4);
  int* cursor = (int*)carve((size_t)NN * 4);
  int* slist  = (int*)carve((size_t)NE * 4);
  int* e2p    = (int*)carve((size_t)NE * 4);
  float* bfac = (float*)carve((size_t)NN * 4);
  int* bsum   = (int*)carve((size_t)SCAN_NB * 4);
  int* boff   = (int*)carve((size_t)SCAN_NB * 4);
  u16* wB00t  = (u16*)carve(2048 * 2);
  u16* wqt    = (u16*)carve(16384 * 2);
  u16* BGQ    = (u16*)carve((size_t)131072 * 2);
  u16* wB1t   = (u16*)carve(512 * 2);
  u16* wB2t   = (u16*)carve(4096 * 2);
  u16* wB3t   = (u16*)carve(4096 * 2);
  u16* Bt     = (u16*)carve((size_t)256 * 576 * 2);
  u16* Bt1    = (u16*)carve((size_t)128 * 256 * 2);
  if (off > ws_size) return;

  k_prep_all<<<(PREP_TOTAL + 255) / 256, 256, 0, stream>>>(
      w00, wq, wedge, wk, we1, we2, we3, wv, wskip, w1,
      wB00t, wqt, BGQ, wB1t, wB2t, wB3t, Bt, Bt1, deg);
  k_hist<<<NE / 256, 256, 0, stream>>>(ei, deg);
  k_scan_a<<<SCAN_NB, 256, 0, stream>>>(deg, bsum);
  k_scan_b<<<1, 256, 0, stream>>>(bsum, boff, rowptr);
  k_scan_c<<<SCAN_NB, 256, 0, stream>>>(deg, boff, rowptr, cursor);
  k_scatter<<<NE / 256, 256, 0, stream>>>(ei, cursor, slist, e2p);
  k_ng<<<(NN + 63) / 64, 256, 0, stream>>>(x, wB00t, b00, wqt, bq, BGQ, x1g, Gg, Qkg);
  k_edge_mlp<<<NE / EPB, 256, 0, stream>>>(ea, wB1t, wB2t, wB3t, be1, be2, be3, e2p, e3g);
  k_attn<<<NN / 4, 256, 0, stream>>>(rowptr, slist, yg, x1g, Gg, Qkg, e3g, bfac);
  k_posthead<<<(NN + PM - 1) / PM, 256, 0, stream>>>(
      Gg, yg, x1g, Bt, bfac, bedge, bv, bskip, lng, lnb, Bt1, b1, w2, b2, outg);
}